// Round 6
// baseline (576.944 us; speedup 1.0000x reference)
//
#include <hip/hip_runtime.h>
#include <hip/hip_bf16.h>

#define HH   512
#define BB   8192
#define WIDTH (1.0f/16.0f)
#define NBLK 1024u

typedef __attribute__((ext_vector_type(8))) short  short8;   // 8 bf16 = 4 VGPRs
typedef __attribute__((ext_vector_type(4))) float  floatx4;

typedef const __attribute__((address_space(1))) void* gptr_t;
typedef __attribute__((address_space(3))) void*       lptr_t;

__device__ __forceinline__ void gload_lds16(const void* g, void* l) {
    // async global->LDS, 16B per lane; LDS dst = wave-uniform base + lane*16
    __builtin_amdgcn_global_load_lds((gptr_t)g, (lptr_t)l, 16, 0, 0);
}

__device__ __forceinline__ float tanh_fast(float x) {
    float e = __expf(2.0f * x);
    return 1.0f - 2.0f * __builtin_amdgcn_rcpf(e + 1.0f);
}

// Device-scope grid barrier (G16 pattern): release-fence + agent atomic arrive,
// acquire spin. One-shot counter per barrier; host memsets them each iteration.
// All 1024 blocks are co-resident by construction (4 blocks/CU: 32KB LDS of 160,
// 16 of 32 waves, VGPR<=128 enforced by __launch_bounds__(256,4)).
__device__ __forceinline__ void grid_barrier(unsigned* cnt) {
    __syncthreads();
    if (threadIdx.x == 0) {
        __threadfence();                                     // release our writes
        __hip_atomic_fetch_add(cnt, 1u, __ATOMIC_ACQ_REL, __HIP_MEMORY_SCOPE_AGENT);
        while (__hip_atomic_load(cnt, __ATOMIC_ACQUIRE, __HIP_MEMORY_SCOPE_AGENT) < NBLK)
            __builtin_amdgcn_s_sleep(2);
        __threadfence();                                     // acquire all writes
    }
    __syncthreads();
}

// ============ fused: prep | grid-bar | gemm1 | grid-bar | gemm2 =============
__global__ __launch_bounds__(256, 4) void fused_kernel(
        const float* __restrict__ vin,            // (8192,1024) fp32
        const float* __restrict__ ld,             // (8192,1)
        const float* __restrict__ W1,             // (512,512) fp32 [k][n]
        const float* __restrict__ b1,             // (512)
        const float* __restrict__ W2,             // (512,8192) fp32 [k][n]
        const float* __restrict__ b2,             // (8192)
        float* __restrict__ vout,                 // (8192,1024) fp32
        float* __restrict__ ldout,                // (8192) fp32
        __hip_bfloat16* __restrict__ Abf,         // (8192,512) bf16 ws
        __hip_bfloat16* __restrict__ W1T,         // (512,512)  bf16 [n][k] ws
        __hip_bfloat16* __restrict__ W2T,         // (8192,512) bf16 [n][k] ws
        __hip_bfloat16* __restrict__ hM,          // (8192,512) bf16 ws
        unsigned* __restrict__ cnt) {             // 2 barrier counters (memset 0)
    __shared__ __align__(16) char smem[32768];
    int bid = blockIdx.x, tid = threadIdx.x;
    int lane = tid & 63;
    int wv = tid >> 6;
    int q = lane >> 4, cx = lane & 15;
    int srow = tid >> 3;                          // staging row component
    int skw  = ((tid & 7) ^ (srow & 7)) * 8;      // inverse-swizzled k offset (elems)

    // ---------------- stage P: transposes + prep_v (4224 units, grid-stride) ----
    for (int u = bid; u < 4224; u += 1024) {
        if (u < 2176) {
            // 64k x 32n transpose tile: fp32 [k][n] -> bf16 [n][k]; dst rows get a
            // full 128B store (8 lanes x uint4). LDS [64][37] fp32: <=2-way banks.
            const float* src;  __hip_bfloat16* dst;  int cols, r0, c0;
            if (u < 2048) { src = W2; dst = W2T; cols = 8192; r0 = (u >> 8) * 64; c0 = (u & 255) * 32; }
            else { int t = u - 2048; src = W1; dst = W1T; cols = 512; r0 = (t >> 4) * 64; c0 = (t & 15) * 32; }
            float* tile = (float*)smem;           // 64*37 = 2368 floats (9.25 KB)
            #pragma unroll
            for (int i = 0; i < 2; ++i) {
                int c = i * 256 + tid, kr = c >> 3, ng = c & 7;
                float4 f = *(const float4*)(src + (size_t)(r0 + kr) * cols + c0 + ng * 4);
                float* tp = tile + kr * 37 + ng * 4;
                tp[0] = f.x; tp[1] = f.y; tp[2] = f.z; tp[3] = f.w;
            }
            __syncthreads();
            int n = tid >> 3, kc = tid & 7;
            union { __hip_bfloat16 h[8]; uint4 v; } o;
            #pragma unroll
            for (int j = 0; j < 8; ++j)
                o.h[j] = __float2bfloat16(tile[(kc * 8 + j) * 37 + n]);
            *(uint4*)(dst + (size_t)(c0 + n) * 512 + r0 + kc * 8) = o.v;
            __syncthreads();                      // LDS reused by next unit
        } else {
            // prep_v: vout[:, :512] = vin[:, :512]; Abf = bf16(v_p - 0.5); ldout = ld
            int b = u - 2176;                     // 0..2047
            int i = b * 256 + tid;
            int r = i >> 6, c = i & 63;
            const float4* src = (const float4*)(vin + (size_t)r * 1024 + c * 8);
            float4 f0 = src[0], f1 = src[1];
            float4* dst = (float4*)(vout + (size_t)r * 1024 + c * 8);
            dst[0] = f0; dst[1] = f1;
            union { __hip_bfloat16 h[8]; uint4 v; } u8;
            u8.h[0] = __float2bfloat16(f0.x - 0.5f); u8.h[1] = __float2bfloat16(f0.y - 0.5f);
            u8.h[2] = __float2bfloat16(f0.z - 0.5f); u8.h[3] = __float2bfloat16(f0.w - 0.5f);
            u8.h[4] = __float2bfloat16(f1.x - 0.5f); u8.h[5] = __float2bfloat16(f1.y - 0.5f);
            u8.h[6] = __float2bfloat16(f1.z - 0.5f); u8.h[7] = __float2bfloat16(f1.w - 0.5f);
            *(uint4*)(Abf + (size_t)r * 512 + c * 8) = u8.v;
            if (tid < 4) { int row = b * 4 + tid; ldout[row] = ld[row]; }
        }
    }
    grid_barrier(cnt);

    // ---------------- stage G1: h = tanh(Abf @ W1T^T + b1), 64x64 tiles ---------
    // 1024 tiles = 1 per block (full-machine TLP; was 256 blocks = 1/CU).
    {
        short* ldsA = (short*)smem;               // [64][64] shorts, 8 KB
        short* ldsB = (short*)(smem + 8192);      // [64][64] shorts, 8 KB
        int rowBase = (bid >> 3) * 64;            // 128 row-tiles
        int colBase = (bid & 7) * 64;             // 8 col-tiles
        floatx4 acc1[4] = {};
        for (int k0 = 0; k0 < HH; k0 += 64) {
            #pragma unroll
            for (int j = 0; j < 2; ++j) {         // 512 chunks per matrix
                int row = j * 32 + srow;
                unsigned loff = __builtin_amdgcn_readfirstlane((unsigned)((j * 256 + (tid & 192)) * 16));
                gload_lds16(Abf + (size_t)(rowBase + row) * HH + k0 + skw, (char*)ldsA + loff);
                gload_lds16(W1T + (size_t)(colBase + row) * HH + k0 + skw, (char*)ldsB + loff);
            }
            __syncthreads();
            #pragma unroll
            for (int s = 0; s < 2; ++s) {         // verified 8-slot XOR swizzle reads
                short8 a = *(const short8*)(ldsA + (wv * 16 + cx) * 64
                                                 + (((s * 4 + q) ^ (cx & 7)) << 3));
                #pragma unroll
                for (int nt = 0; nt < 4; ++nt) {
                    short8 b = *(const short8*)(ldsB + (nt * 16 + cx) * 64
                                                     + (((s * 4 + q) ^ (cx & 7)) << 3));
                    acc1[nt] = __builtin_amdgcn_mfma_f32_16x16x32_bf16(a, b, acc1[nt], 0, 0, 0);
                }
            }
            __syncthreads();
        }
        #pragma unroll
        for (int nt = 0; nt < 4; ++nt) {
            int col = colBase + nt * 16 + cx;
            float bb = b1[col];
            #pragma unroll
            for (int r = 0; r < 4; ++r) {
                int row = rowBase + wv * 16 + q * 4 + r;   // C: col=lane&15, row=quad*4+reg
                hM[(size_t)row * HH + col] = __float2bfloat16(tanh_fast(acc1[nt][r] + bb));
            }
        }
    }
    grid_barrier(cnt + 1);

    // ---------------- stage G2: fused gemm2 (verified body), 4 tiles/block ------
    short* ldsA = (short*)smem;                   // [128][64] shorts
    short* ldsB = (short*)(smem + 16384);
    float* ldsE = (float*)smem;                   // epilogue: 4 waves x 16x76 fp32
    int wr = wv >> 1, wc = wv & 1;
    for (int g = 0; g < 4; ++g) {
        int tt = g * 1024 + bid;                  // 0..4095, XCD swizzle preserved
        int xcd = tt & 7, w = tt >> 3;
        int by  = xcd * 8 + (w & 7);
        int bx  = w >> 3;                         // 0..63
        int rowBase = by * 128;
        int colBase = bx * 128;
        floatx4 acc[4][4] = {};

        for (int k0 = 0; k0 < HH; k0 += 64) {
            #pragma unroll
            for (int j = 0; j < 4; ++j) {         // 1024 chunks per matrix
                int row = j * 32 + srow;
                unsigned loff = __builtin_amdgcn_readfirstlane((unsigned)((j * 256 + (tid & 192)) * 16));
                gload_lds16(hM  + (size_t)(rowBase + row) * HH + k0 + skw, (char*)ldsA + loff);
                gload_lds16(W2T + (size_t)(colBase + row) * HH + k0 + skw, (char*)ldsB + loff);
            }
            __syncthreads();
            #pragma unroll
            for (int s = 0; s < 2; ++s) {
                short8 a[4], b[4];
                #pragma unroll
                for (int mt = 0; mt < 4; ++mt)
                    a[mt] = *(const short8*)(ldsA + (wr * 64 + mt * 16 + cx) * 64
                                                  + (((s * 4 + q) ^ (cx & 7)) << 3));
                #pragma unroll
                for (int nt = 0; nt < 4; ++nt)
                    b[nt] = *(const short8*)(ldsB + (wc * 64 + nt * 16 + cx) * 64
                                                  + (((s * 4 + q) ^ (cx & 7)) << 3));
                #pragma unroll
                for (int mt = 0; mt < 4; ++mt)
                    #pragma unroll
                    for (int nt = 0; nt < 4; ++nt)
                        acc[mt][nt] = __builtin_amdgcn_mfma_f32_16x16x32_bf16(a[mt], b[nt], acc[mt][nt], 0, 0, 0);
            }
            __syncthreads();                      // last iter: epilogue may reuse LDS
        }

        float b2v[4];
        #pragma unroll
        for (int nt = 0; nt < 4; ++nt) b2v[nt] = b2[colBase + wc * 64 + nt * 16 + cx];

        float* myTile = ldsE + wv * (16 * 76);    // wave-private: no barrier needed
        int rowL  = lane & 15;
        int gL    = lane >> 4;
        int gAbs  = bx * 8 + wc * 4 + gL;

        #pragma unroll
        for (int mt = 0; mt < 4; ++mt) {
            #pragma unroll
            for (int nt = 0; nt < 4; ++nt)
                #pragma unroll
                for (int r = 0; r < 4; ++r)
                    myTile[(q * 4 + r) * 76 + nt * 16 + cx] = acc[mt][nt][r] + b2v[nt];

            floatx4 x0 = *(const floatx4*)(myTile + rowL * 76 + gL * 16);
            floatx4 x1 = *(const floatx4*)(myTile + rowL * 76 + gL * 16 + 4);
            floatx4 x2 = *(const floatx4*)(myTile + rowL * 76 + gL * 16 + 8);
            floatx4 x3 = *(const floatx4*)(myTile + rowL * 76 + gL * 16 + 12);
            float xs[16] = { x0[0],x0[1],x0[2],x0[3], x1[0],x1[1],x1[2],x1[3],
                             x2[0],x2[1],x2[2],x2[3], x3[0],x3[1],x3[2],x3[3] };

            int row = rowBase + wr * 64 + mt * 16 + rowL;
            float v = vin[(size_t)row * 1024 + 512 + gAbs];
            int k = (int)ceilf(v * 16.0f) - 1;    // exact searchsorted('left')-1
            k = min(15, max(0, k));

            float s = 0.0f, csum = 0.0f, ek = 0.0f;
            #pragma unroll
            for (int j = 0; j < 16; ++j) {
                float e2 = __expf(2.0f * xs[j]);
                float t  = 1.0f - 2.0f * __builtin_amdgcn_rcpf(e2 + 1.0f);   // tanh
                float e  = __expf(t);             // t in [-1,1]: no max-subtract needed
                csum += (j < k)  ? e : 0.0f;
                ek    = (j == k) ? e : ek;
                s += e;
            }
            float rs = __builtin_amdgcn_rcpf(s);
            float pk  = ek * rs;
            float ylo = csum * rs;
            float alpha = (v - (float)k * WIDTH) * 16.0f;
            vout[(size_t)row * 1024 + 512 + gAbs] = ylo + alpha * pk;

            float logp = __logf(pk);
            logp += __shfl_xor(logp, 16, 64);     // reduce over 4 groups sharing a row
            logp += __shfl_xor(logp, 32, 64);
            if (lane < 16) atomicAdd(ldout + row, -logp);   // XCD-local panel
        }
        __syncthreads();                          // next tile's staging reuses LDS
    }
}

extern "C" void kernel_launch(void* const* d_in, const int* in_sizes, int n_in,
                              void* d_out, int out_size, void* d_ws, size_t ws_size,
                              hipStream_t stream) {
    const float* vin = (const float*)d_in[0];
    const float* ld  = (const float*)d_in[1];
    const float* W1  = (const float*)d_in[2];
    const float* b1  = (const float*)d_in[3];
    const float* W2  = (const float*)d_in[4];
    const float* b2  = (const float*)d_in[5];
    float* vout  = (float*)d_out;
    float* ldout = vout + (size_t)BB * 1024;

    char* ws = (char*)d_ws;                                    // layout (16B aligned):
    __hip_bfloat16* Abf = (__hip_bfloat16*)(ws);               //  8 MB  @ 0
    __hip_bfloat16* W1T = (__hip_bfloat16*)(ws + 8388608);     //  0.5MB
    __hip_bfloat16* W2T = (__hip_bfloat16*)(ws + 8912896);     //  8 MB
    __hip_bfloat16* hM  = (__hip_bfloat16*)(ws + 17301504);    //  8 MB
    unsigned* cnt       = (unsigned*)(ws + 25690112);          //  8 B  barrier counters

    hipMemsetAsync(cnt, 0, 8, stream);            // one-shot barrier counters
    fused_kernel<<<NBLK, 256, 0, stream>>>(vin, ld, W1, b1, W2, b2,
                                           vout, ldout, Abf, W1T, W2T, hM, cnt);
}

// Round 7
// 195.229 us; speedup vs baseline: 2.9552x; 2.9552x over previous
//
#include <hip/hip_runtime.h>
#include <hip/hip_bf16.h>

#define HH   512
#define BB   8192
#define WIDTH (1.0f/16.0f)

typedef __attribute__((ext_vector_type(8))) short  short8;   // 8 bf16 = 4 VGPRs
typedef __attribute__((ext_vector_type(4))) float  floatx4;

typedef const __attribute__((address_space(1))) void* gptr_t;
typedef __attribute__((address_space(3))) void*       lptr_t;

__device__ __forceinline__ void gload_lds16(const void* g, void* l) {
    // async global->LDS, 16B per lane; LDS dst = wave-uniform base + lane*16
    __builtin_amdgcn_global_load_lds((gptr_t)g, (lptr_t)l, 16, 0, 0);
}

__device__ __forceinline__ float tanh_fast(float x) {
    float e = __expf(2.0f * x);
    return 1.0f - 2.0f * __builtin_amdgcn_rcpf(e + 1.0f);
}

// ---- prep_all: transposes (64k x 32n tiles, full-128B stores) + prep_v ----
// Code validated inside round-6 fused kernel; now a standalone 4224-block dispatch.
// units 0..2047: W2 transpose; 2048..2175: W1 transpose; 2176..4223: prep_v.
__global__ void prep_all(const float* __restrict__ vin, const float* __restrict__ W1,
                         const float* __restrict__ W2, const float* __restrict__ ld,
                         float* __restrict__ vout, float* __restrict__ ldout,
                         __hip_bfloat16* __restrict__ Abf,
                         __hip_bfloat16* __restrict__ W1T,
                         __hip_bfloat16* __restrict__ W2T) {
    __shared__ __align__(16) float tile[64 * 37];   // 9.25 KB, <=2-way banks
    int u = blockIdx.x, tid = threadIdx.x;
    if (u < 2176) {
        const float* src;  __hip_bfloat16* dst;  int cols, r0, c0;
        if (u < 2048) { src = W2; dst = W2T; cols = 8192; r0 = (u >> 8) * 64; c0 = (u & 255) * 32; }
        else { int t = u - 2048; src = W1; dst = W1T; cols = 512; r0 = (t >> 4) * 64; c0 = (t & 15) * 32; }
        #pragma unroll
        for (int i = 0; i < 2; ++i) {
            int c = i * 256 + tid, kr = c >> 3, ng = c & 7;
            float4 f = *(const float4*)(src + (size_t)(r0 + kr) * cols + c0 + ng * 4);
            float* tp = tile + kr * 37 + ng * 4;
            tp[0] = f.x; tp[1] = f.y; tp[2] = f.z; tp[3] = f.w;
        }
        __syncthreads();
        int n = tid >> 3, kc = tid & 7;
        union { __hip_bfloat16 h[8]; uint4 v; } o;
        #pragma unroll
        for (int j = 0; j < 8; ++j)
            o.h[j] = __float2bfloat16(tile[(kc * 8 + j) * 37 + n]);
        *(uint4*)(dst + (size_t)(c0 + n) * 512 + r0 + kc * 8) = o.v;   // 128B/row
    } else {
        // prep_v: vout[:, :512] = vin[:, :512]; Abf = bf16(v_p - 0.5); ldout = ld
        int b = u - 2176;                     // 0..2047
        int i = b * 256 + tid;
        int r = i >> 6, c = i & 63;
        const float4* src = (const float4*)(vin + (size_t)r * 1024 + c * 8);
        float4 f0 = src[0], f1 = src[1];
        float4* dst = (float4*)(vout + (size_t)r * 1024 + c * 8);
        dst[0] = f0; dst[1] = f1;
        union { __hip_bfloat16 h[8]; uint4 v; } u8;
        u8.h[0] = __float2bfloat16(f0.x - 0.5f); u8.h[1] = __float2bfloat16(f0.y - 0.5f);
        u8.h[2] = __float2bfloat16(f0.z - 0.5f); u8.h[3] = __float2bfloat16(f0.w - 0.5f);
        u8.h[4] = __float2bfloat16(f1.x - 0.5f); u8.h[5] = __float2bfloat16(f1.y - 0.5f);
        u8.h[6] = __float2bfloat16(f1.z - 0.5f); u8.h[7] = __float2bfloat16(f1.w - 0.5f);
        *(uint4*)(Abf + (size_t)r * 512 + c * 8) = u8.v;
        if (tid < 4) { int row = b * 4 + tid; ldout[row] = ld[row]; }
    }
}

// ------- GEMM1: h = tanh(Abf @ W1T^T + b1), 64x64 tiles, 1024 blocks -------
// 4 blocks/CU (full-machine TLP; old version had 256 blocks = 1/CU and exposed
// every staging latency). Body validated inside round-6 fused kernel.
__global__ __launch_bounds__(256, 4) void gemm1_kernel(
        const __hip_bfloat16* __restrict__ Abf,   // (8192,512) bf16, = v_p - 0.5
        const __hip_bfloat16* __restrict__ W1T,   // (512,512) [n][k] bf16
        const float* __restrict__ b1,
        __hip_bfloat16* __restrict__ hM) {        // (8192,512) bf16
    __shared__ __align__(16) char smem[16384];
    short* ldsA = (short*)smem;                   // [64][64] shorts, 8 KB
    short* ldsB = (short*)(smem + 8192);          // [64][64] shorts, 8 KB
    int tid = threadIdx.x;
    int lane = tid & 63;
    int wv = tid >> 6;
    int q = lane >> 4, cx = lane & 15;
    int srow = tid >> 3;                          // 0..31
    int skw  = ((tid & 7) ^ (srow & 7)) * 8;      // inverse-swizzled k offset (elems)
    int bid = blockIdx.x;
    int rowBase = (bid >> 3) * 64;                // 128 row-tiles
    int colBase = (bid & 7) * 64;                 // 8 col-tiles
    floatx4 acc1[4] = {};

    for (int k0 = 0; k0 < HH; k0 += 64) {
        #pragma unroll
        for (int j = 0; j < 2; ++j) {             // 512 chunks per matrix
            int row = j * 32 + srow;
            unsigned loff = __builtin_amdgcn_readfirstlane((unsigned)((j * 256 + (tid & 192)) * 16));
            gload_lds16(Abf + (size_t)(rowBase + row) * HH + k0 + skw, (char*)ldsA + loff);
            gload_lds16(W1T + (size_t)(colBase + row) * HH + k0 + skw, (char*)ldsB + loff);
        }
        __syncthreads();
        #pragma unroll
        for (int s = 0; s < 2; ++s) {             // verified 8-slot XOR swizzle reads
            short8 a = *(const short8*)(ldsA + (wv * 16 + cx) * 64
                                             + (((s * 4 + q) ^ (cx & 7)) << 3));
            #pragma unroll
            for (int nt = 0; nt < 4; ++nt) {
                short8 b = *(const short8*)(ldsB + (nt * 16 + cx) * 64
                                                 + (((s * 4 + q) ^ (cx & 7)) << 3));
                acc1[nt] = __builtin_amdgcn_mfma_f32_16x16x32_bf16(a, b, acc1[nt], 0, 0, 0);
            }
        }
        __syncthreads();
    }
    #pragma unroll
    for (int nt = 0; nt < 4; ++nt) {
        int col = colBase + nt * 16 + cx;
        float bb = b1[col];
        #pragma unroll
        for (int r = 0; r < 4; ++r) {
            int row = rowBase + wv * 16 + q * 4 + r;   // C: col=lane&15, row=quad*4+reg
            hM[(size_t)row * HH + col] = __float2bfloat16(tanh_fast(acc1[nt][r] + bb));
        }
    }
}

// ------- GEMM2 fused: net=tanh(h@W2+b2); softmax(16); spline; atomic log-dens -------
// UNCHANGED from rounds 3-5 (verified: ~92 us, conflicts 1.05M, MfmaUtil 33%).
__global__ __launch_bounds__(256, 4) void gemm2_kernel(
        const __hip_bfloat16* __restrict__ hM,    // (8192,512) bf16
        const __hip_bfloat16* __restrict__ W2T,   // (8192,512) [n][k] bf16
        const float* __restrict__ b2,             // (8192) fp32
        const float* __restrict__ vin,            // (8192,1024) fp32, active cols 512..1023
        float* __restrict__ vout,                 // (8192,1024) fp32
        float* __restrict__ ldout) {              // (8192) fp32, pre-initialized to ld
    __shared__ __align__(16) char smem[32768];    // A: 16K, B: 16K; epilogue reuses
    short* ldsA = (short*)smem;                   // [128][64] shorts
    short* ldsB = (short*)(smem + 16384);         // [128][64] shorts
    float* ldsE = (float*)smem;                   // epilogue: 4 waves x 16x76 fp32 (19456 B)
    int tid = threadIdx.x;
    int lane = tid & 63;
    int wv = tid >> 6, wr = wv >> 1, wc = wv & 1;
    int q = lane >> 4, cx = lane & 15;
    int srow = tid >> 3;                          // staging row 0..31 (+j*32)
    int skw  = ((tid & 7) ^ (srow & 7)) * 8;      // inverse-swizzled k offset (elements)
    // XCD swizzle: round-robin dispatch puts bid&7 on XCD (bid&7); give each XCD a
    // contiguous 8-block y-panel and iterate x within it.
    int bid = blockIdx.x;                         // 0..4095
    int xcd = bid & 7, w = bid >> 3;
    int by  = xcd * 8 + (w & 7);                  // y panel: 1024 rows per XCD
    int bx  = w >> 3;                             // 0..63
    int rowBase = by * 128;
    int colBase = bx * 128;
    floatx4 acc[4][4] = {};

    for (int k0 = 0; k0 < HH; k0 += 64) {
        #pragma unroll
        for (int j = 0; j < 4; ++j) {             // 1024 chunks per matrix
            int row = j * 32 + srow;
            unsigned loff = __builtin_amdgcn_readfirstlane((unsigned)((j * 256 + (tid & 192)) * 16));
            gload_lds16(hM  + (size_t)(rowBase + row) * HH + k0 + skw, (char*)ldsA + loff);
            gload_lds16(W2T + (size_t)(colBase + row) * HH + k0 + skw, (char*)ldsB + loff);
        }
        __syncthreads();
        #pragma unroll
        for (int s = 0; s < 2; ++s) {             // logical k-chunk = s*4+q, slot = ^(row&7)
            short8 a[4], b[4];
            #pragma unroll
            for (int mt = 0; mt < 4; ++mt)
                a[mt] = *(const short8*)(ldsA + (wr * 64 + mt * 16 + cx) * 64
                                              + (((s * 4 + q) ^ (cx & 7)) << 3));
            #pragma unroll
            for (int nt = 0; nt < 4; ++nt)
                b[nt] = *(const short8*)(ldsB + (wc * 64 + nt * 16 + cx) * 64
                                              + (((s * 4 + q) ^ (cx & 7)) << 3));
            #pragma unroll
            for (int mt = 0; mt < 4; ++mt)
                #pragma unroll
                for (int nt = 0; nt < 4; ++nt)
                    acc[mt][nt] = __builtin_amdgcn_mfma_f32_16x16x32_bf16(a[mt], b[nt], acc[mt][nt], 0, 0, 0);
        }
        __syncthreads();   // staging LDS dead after last iter -> epilogue may reuse
    }

    float b2v[4];
    #pragma unroll
    for (int nt = 0; nt < 4; ++nt) b2v[nt] = b2[colBase + wc * 64 + nt * 16 + cx];

    float* myTile = ldsE + wv * (16 * 76);        // wave-private: no barrier needed
    int rowL  = lane & 15;                         // read-phase: lane's row within 16-row slab
    int gL    = lane >> 4;                         // lane's group (0..3) within wave's 64 cols
    int gAbs  = bx * 8 + wc * 4 + gL;             // absolute h-group index

    #pragma unroll
    for (int mt = 0; mt < 4; ++mt) {
        // write phase: C-layout slab (16 rows x 64 cols) -> LDS, +b2 folded in
        #pragma unroll
        for (int nt = 0; nt < 4; ++nt)
            #pragma unroll
            for (int r = 0; r < 4; ++r)
                myTile[(q * 4 + r) * 76 + nt * 16 + cx] = acc[mt][nt][r] + b2v[nt];
        // no __syncthreads: tile is wave-private; compiler inserts lgkmcnt wait

        // read phase: lane owns (row=rowL, group=gL): 16 contiguous floats
        floatx4 x0 = *(const floatx4*)(myTile + rowL * 76 + gL * 16);
        floatx4 x1 = *(const floatx4*)(myTile + rowL * 76 + gL * 16 + 4);
        floatx4 x2 = *(const floatx4*)(myTile + rowL * 76 + gL * 16 + 8);
        floatx4 x3 = *(const floatx4*)(myTile + rowL * 76 + gL * 16 + 12);
        float xs[16] = { x0[0],x0[1],x0[2],x0[3], x1[0],x1[1],x1[2],x1[3],
                         x2[0],x2[1],x2[2],x2[3], x3[0],x3[1],x3[2],x3[3] };

        int row = rowBase + wr * 64 + mt * 16 + rowL;
        float v = vin[(size_t)row * 1024 + 512 + gAbs];
        int k = (int)ceilf(v * 16.0f) - 1;        // exact searchsorted('left')-1 (v*16 exact)
        k = min(15, max(0, k));

        float s = 0.0f, csum = 0.0f, ek = 0.0f;
        #pragma unroll
        for (int j = 0; j < 16; ++j) {
            float e2 = __expf(2.0f * xs[j]);
            float t  = 1.0f - 2.0f * __builtin_amdgcn_rcpf(e2 + 1.0f);   // tanh
            float e  = __expf(t);                 // t in [-1,1]: no max-subtract needed
            csum += (j < k)  ? e : 0.0f;
            ek    = (j == k) ? e : ek;
            s += e;
        }
        float rs = __builtin_amdgcn_rcpf(s);
        float pk  = ek * rs;
        float ylo = csum * rs;
        float alpha = (v - (float)k * WIDTH) * 16.0f;
        vout[(size_t)row * 1024 + 512 + gAbs] = ylo + alpha * pk;

        float logp = __logf(pk);
        logp += __shfl_xor(logp, 16, 64);          // reduce over 4 groups sharing a row
        logp += __shfl_xor(logp, 32, 64);
        if (lane < 16) atomicAdd(ldout + row, -logp);   // XCD-local: row in this XCD's panel
    }
}

extern "C" void kernel_launch(void* const* d_in, const int* in_sizes, int n_in,
                              void* d_out, int out_size, void* d_ws, size_t ws_size,
                              hipStream_t stream) {
    const float* vin = (const float*)d_in[0];
    const float* ld  = (const float*)d_in[1];
    const float* W1  = (const float*)d_in[2];
    const float* b1  = (const float*)d_in[3];
    const float* W2  = (const float*)d_in[4];
    const float* b2  = (const float*)d_in[5];
    float* vout  = (float*)d_out;
    float* ldout = vout + (size_t)BB * 1024;

    char* ws = (char*)d_ws;                                    // layout (16B aligned):
    __hip_bfloat16* Abf = (__hip_bfloat16*)(ws);               //  8 MB  @ 0
    __hip_bfloat16* W1T = (__hip_bfloat16*)(ws + 8388608);     //  0.5MB
    __hip_bfloat16* W2T = (__hip_bfloat16*)(ws + 8912896);     //  8 MB
    __hip_bfloat16* hM  = (__hip_bfloat16*)(ws + 17301504);    //  8 MB  (total ~24.5MB)

    prep_all<<<4224, 256, 0, stream>>>(vin, W1, W2, ld, vout, ldout, Abf, W1T, W2T);
    gemm1_kernel<<<1024, 256, 0, stream>>>(Abf, W1T, b1, hM);
    gemm2_kernel<<<4096, 256, 0, stream>>>(hM, W2T, b2, vin, vout, ldout);
}